// Round 5
// baseline (55.530 us; speedup 1.0000x reference)
//
#include <hip/hip_runtime.h>
#include <math.h>

#define B_  8
#define L_  4096
#define C_  256
#define TL  16

// Fused deformable conv1d.
// Grid (L_/TL, B_), 256 threads (4 waves). Wave g owns positions lb..lb+3.
// Phase 1: two conv passes (offset, mask) -> batched 12-chain butterfly,
//          sums replicated in all lanes (no LDS, no barrier).
// Phase 2: wave samples its own 4 positions, c = lane*4 -> 1KB coalesced
//          row loads; writes s_tile with granule-XOR swizzle.
// Phase 3: transpose write-out, float4 along l.
__global__ __launch_bounds__(256, 6)
void dconv1d_kernel(const float* __restrict__ x,
                    const float* __restrict__ w_off,
                    const float* __restrict__ b_off,
                    const float* __restrict__ w_mask,
                    const float* __restrict__ b_mask,
                    float* __restrict__ out) {
    __shared__ float s_tile[TL * C_];   // 16 KB

    const int tid  = threadIdx.x;
    const int lane = tid & 63;
    const int g    = tid >> 6;          // wave 0..3
    const int l0   = blockIdx.x * TL;
    const int lb   = l0 + g * 4;        // wave's first position
    const int b    = blockIdx.y;
    const float* __restrict__ xb = x + (size_t)b * L_ * C_;

    // ---- phase 1: conv sums for this wave's 4 positions ----
    float prm[2][4][3];   // [pass][pos][k], replicated across lanes

    #pragma unroll
    for (int pass = 0; pass < 2; ++pass) {
        const float* __restrict__ wsrc = pass ? w_mask : w_off;
        // lane owns channels lane*4..lane*4+3 for 3 outputs: 36 regs
        float wr[3][12];
        #pragma unroll
        for (int o = 0; o < 3; ++o) {
            const float4* wp =
                reinterpret_cast<const float4*>(wsrc + o * (C_ * 3) + lane * 12);
            float4 q0 = wp[0], q1 = wp[1], q2 = wp[2];
            wr[o][0]=q0.x; wr[o][1] =q0.y; wr[o][2] =q0.z; wr[o][3] =q0.w;
            wr[o][4]=q1.x; wr[o][5] =q1.y; wr[o][6] =q1.z; wr[o][7] =q1.w;
            wr[o][8]=q2.x; wr[o][9] =q2.y; wr[o][10]=q2.z; wr[o][11]=q2.w;
        }
        float acc[4][3];
        #pragma unroll
        for (int i = 0; i < 4; ++i)
            #pragma unroll
            for (int o = 0; o < 3; ++o) acc[i][o] = 0.f;

        // 6 rows cover positions lb..lb+3, taps -1..+1
        #pragma unroll
        for (int rr = 0; rr < 6; ++rr) {
            const int row = lb - 1 + rr;
            if (row >= 0 && row < L_) {
                const float4 xv = *reinterpret_cast<const float4*>(
                    xb + (size_t)row * C_ + lane * 4);
                #pragma unroll
                for (int t = 0; t < 3; ++t) {
                    const int i = rr - t;            // compile-time per (rr,t)
                    if (i >= 0 && i < 4) {
                        #pragma unroll
                        for (int o = 0; o < 3; ++o)
                            acc[i][o] += xv.x * wr[o][0 + t] + xv.y * wr[o][3 + t]
                                       + xv.z * wr[o][6 + t] + xv.w * wr[o][9 + t];
                    }
                }
            }
        }
        // batched butterfly all-reduce: 12 independent chains per step
        #pragma unroll
        for (int s = 1; s < 64; s <<= 1) {
            #pragma unroll
            for (int i = 0; i < 4; ++i)
                #pragma unroll
                for (int o = 0; o < 3; ++o)
                    acc[i][o] += __shfl_xor(acc[i][o], s, 64);
        }
        #pragma unroll
        for (int i = 0; i < 4; ++i)
            #pragma unroll
            for (int o = 0; o < 3; ++o)
                prm[pass][i][o] = acc[i][o];
    }

    // ---- phase 2: sample own 4 positions; c = lane*4 (coalesced rows) ----
    const int cbase = lane * 4;
    #pragma unroll
    for (int i = 0; i < 4; ++i) {
        const int ll = g * 4 + i;
        const int l  = lb + i;
        float4 v = make_float4(0.f, 0.f, 0.f, 0.f);
        #pragma unroll
        for (int k = 0; k < 3; ++k) {
            const float off = prm[0][i][k] + b_off[k];
            const float pos = fminf(fmaxf((float)l + off, 0.0f), (float)(L_ - 1));
            const float flf = floorf(pos);
            const int   fl  = (int)flf;
            const int   ce  = min(fl + 1, L_ - 1);
            const float a   = pos - flf;
            const float z   = prm[1][i][k] + b_mask[k];
            const float m   = 1.0f / (1.0f + __expf(-z));
            const float4 xf = *reinterpret_cast<const float4*>(
                xb + (size_t)fl * C_ + cbase);
            const float4 xc = *reinterpret_cast<const float4*>(
                xb + (size_t)ce * C_ + cbase);
            v.x += (xf.x + a * (xc.x - xf.x)) * m;
            v.y += (xf.y + a * (xc.y - xf.y)) * m;
            v.z += (xf.z + a * (xc.z - xf.z)) * m;
            v.w += (xf.w + a * (xc.w - xf.w)) * m;
        }
        // granule-XOR swizzle: channel-granule (=lane) stored at slot lane^ll
        *reinterpret_cast<float4*>(&s_tile[ll * C_ + ((lane ^ ll) << 2)]) = v;
    }
    __syncthreads();

    // ---- phase 3: transpose write-out, float4 along l ----
    // thread -> (l-quad ql, channel chb); 4 sweeps cover 256 channels
    const int ql  = (tid & 3) * 4;
    const int chb = tid >> 2;            // 0..63
    #pragma unroll
    for (int s = 0; s < 4; ++s) {
        const int ch = chb + s * 64;
        float4 v;
        float* vp = reinterpret_cast<float*>(&v);
        #pragma unroll
        for (int j = 0; j < 4; ++j) {
            const int ll = ql + j;
            vp[j] = s_tile[ll * C_ + ((((ch >> 2) ^ ll) << 2) | (ch & 3))];
        }
        *reinterpret_cast<float4*>(
            &out[((size_t)b * C_ + ch) * L_ + l0 + ql]) = v;
    }
}

extern "C" void kernel_launch(void* const* d_in, const int* in_sizes, int n_in,
                              void* d_out, int out_size, void* d_ws, size_t ws_size,
                              hipStream_t stream) {
    const float* x      = (const float*)d_in[0];
    const float* w_off  = (const float*)d_in[1];
    const float* b_off  = (const float*)d_in[2];
    const float* w_mask = (const float*)d_in[3];
    const float* b_mask = (const float*)d_in[4];
    float* out = (float*)d_out;

    dim3 grid(L_ / TL, B_);
    dconv1d_kernel<<<grid, 256, 0, stream>>>(x, w_off, b_off, w_mask, b_mask, out);
}

// Round 6
// 47.661 us; speedup vs baseline: 1.1651x; 1.1651x over previous
//
#include <hip/hip_runtime.h>
#include <math.h>

#define B_  8
#define L_  4096
#define C_  256

// ======================= Kernel A: conv -> params =========================
// Grid (L_/16, B_), 256 threads. Each wave computes 4 positions' params.
// Output: prm[((b*L + l)*3 + k)] = {floor(pos), alpha, mask, ceil(pos)}
__global__ __launch_bounds__(256, 4)
void params_kernel(const float* __restrict__ x,
                   const float* __restrict__ w_off,
                   const float* __restrict__ b_off,
                   const float* __restrict__ w_mask,
                   const float* __restrict__ b_mask,
                   float4* __restrict__ prm) {
    const int tid  = threadIdx.x;
    const int lane = tid & 63;
    const int w    = tid >> 6;                 // wave 0..3
    const int b    = blockIdx.y;
    const int lbase = blockIdx.x * 16 + w * 4; // first of this wave's 4 positions
    const float* __restrict__ xb = x + (size_t)b * L_ * C_;

    // weights in registers: lane owns channels lane*4 .. lane*4+3
    float w_r[6][12];
    #pragma unroll
    for (int o = 0; o < 6; ++o) {
        const float* ws = (o < 3) ? (w_off + o * (C_ * 3))
                                  : (w_mask + (o - 3) * (C_ * 3));
        const float4* wp = reinterpret_cast<const float4*>(ws + lane * 12);
        float4 q0 = wp[0], q1 = wp[1], q2 = wp[2];
        w_r[o][0]=q0.x; w_r[o][1] =q0.y; w_r[o][2] =q0.z; w_r[o][3] =q0.w;
        w_r[o][4]=q1.x; w_r[o][5] =q1.y; w_r[o][6] =q1.z; w_r[o][7] =q1.w;
        w_r[o][8]=q2.x; w_r[o][9] =q2.y; w_r[o][10]=q2.z; w_r[o][11]=q2.w;
    }

    float acc[4][6];
    #pragma unroll
    for (int i = 0; i < 4; ++i)
        #pragma unroll
        for (int o = 0; o < 6; ++o) acc[i][o] = 0.f;

    // 6 rows cover positions lbase..lbase+3, taps -1..+1 (rows loaded once)
    #pragma unroll
    for (int rr = 0; rr < 6; ++rr) {
        const int row = lbase - 1 + rr;
        if (row >= 0 && row < L_) {
            const float4 xv =
                *reinterpret_cast<const float4*>(xb + (size_t)row * C_ + lane * 4);
            #pragma unroll
            for (int t = 0; t < 3; ++t) {
                const int i = rr - t;               // compile-time per (rr,t)
                if (i >= 0 && i < 4) {
                    #pragma unroll
                    for (int o = 0; o < 6; ++o)
                        acc[i][o] += xv.x * w_r[o][0 + t] + xv.y * w_r[o][3 + t]
                                   + xv.z * w_r[o][6 + t] + xv.w * w_r[o][9 + t];
                }
            }
        }
    }

    // batched butterfly all-reduce: 24 independent chains per step
    #pragma unroll
    for (int s = 1; s < 64; s <<= 1) {
        #pragma unroll
        for (int i = 0; i < 4; ++i)
            #pragma unroll
            for (int o = 0; o < 6; ++o)
                acc[i][o] += __shfl_xor(acc[i][o], s, 64);
    }

    // lane i*3+k writes params for (position lbase+i, tap k)
    #pragma unroll
    for (int i = 0; i < 4; ++i) {
        const int l = lbase + i;
        #pragma unroll
        for (int k = 0; k < 3; ++k) {
            if (lane == i * 3 + k) {
                float off = acc[i][k] + b_off[k];
                float pos = fminf(fmaxf((float)l + off, 0.0f), (float)(L_ - 1));
                float flf = floorf(pos);
                int   fl  = (int)flf;
                float a   = pos - flf;
                float cef = (float)min(fl + 1, L_ - 1);
                float z   = acc[i][k + 3] + b_mask[k];
                float m   = 1.0f / (1.0f + __expf(-z));
                prm[((size_t)b * L_ + l) * 3 + k] = make_float4(flf, a, m, cef);
            }
        }
    }
}

// ======================= Kernel B: gather + transpose =====================
// Tile: 32 l-positions x 64 channels. LDS 8 KB, ~32 VGPR -> 8 blocks/CU.
// Grid ((L_/32)*(C_/64), B_) = (512, 8) = 4096 blocks, 256 threads.
// Writes 128 B full cache lines along l per (b,c) row.
__global__ __launch_bounds__(256, 8)
void sample_kernel(const float* __restrict__ x,
                   const float4* __restrict__ prm,
                   float* __restrict__ out) {
    __shared__ float s_tile[32 * 64];   // 8 KB

    const int tid = threadIdx.x;
    const int l0  = (blockIdx.x >> 2) * 32;       // l-tile
    const int c0  = (blockIdx.x & 3) * 64;        // channel quarter
    const int b   = blockIdx.y;
    const float* __restrict__ xb = x + (size_t)b * L_ * C_;
    const float4* __restrict__ pb = prm + (size_t)b * L_ * 3;

    // phase 2: thread owns channel c0 + (tid&63); wave w does ll = 8w..8w+7
    {
        const int cl = tid & 63;                  // channel within tile
        const int c  = c0 + cl;
        const int w  = tid >> 6;
        #pragma unroll
        for (int i = 0; i < 8; ++i) {
            const int ll = w * 8 + i;
            const int l  = l0 + ll;
            float v = 0.f;
            #pragma unroll
            for (int k = 0; k < 3; ++k) {
                const float4 p = pb[l * 3 + k];   // wave-uniform -> s_load
                const int fl = (int)p.x;
                const int ce = (int)p.w;
                const float xf = xb[fl * C_ + c];
                const float xc = xb[ce * C_ + c];
                v += (xf + p.y * (xc - xf)) * p.z;
            }
            s_tile[ll * 64 + (cl ^ (((ll >> 2) & 7) << 3))] = v;
        }
    }
    __syncthreads();

    // phase 3: transpose write-out, float4 along l (full 128B lines)
    // lane -> lw4 = (tid&7)*4, chh = tid>>3 (0..31); 2 sweeps cover 64 ch
    {
        const int lw4 = (tid & 7) * 4;
        const int chh = tid >> 3;
        #pragma unroll
        for (int s = 0; s < 2; ++s) {
            const int ch = chh + s * 32;          // channel within tile
            float4 v;
            float* vp = reinterpret_cast<float*>(&v);
            #pragma unroll
            for (int j = 0; j < 4; ++j) {
                const int ll = lw4 + j;
                vp[j] = s_tile[ll * 64 + (ch ^ (((ll >> 2) & 7) << 3))];
            }
            *reinterpret_cast<float4*>(
                &out[((size_t)b * C_ + c0 + ch) * L_ + l0 + lw4]) = v;
        }
    }
}

// ==================== Fallback: proven R2 fused kernel ====================
#define TL  32
__global__ __launch_bounds__(256, 4)
void dconv1d_fused(const float* __restrict__ x,
                   const float* __restrict__ w_off,
                   const float* __restrict__ b_off,
                   const float* __restrict__ w_mask,
                   const float* __restrict__ b_mask,
                   float* __restrict__ out) {
    __shared__ float s_tile[TL * C_];
    __shared__ int   s_fl[3][TL];
    __shared__ int   s_ce[3][TL];
    __shared__ float s_al[3][TL];
    __shared__ float s_mk[3][TL];

    const int tid  = threadIdx.x;
    const int lane = tid & 63;
    const int g    = tid >> 6;
    const int l0   = blockIdx.x * TL;
    const int b    = blockIdx.y;
    const float* __restrict__ xb = x + (size_t)b * L_ * C_;

    float w_r[6][12];
    #pragma unroll
    for (int o = 0; o < 6; ++o) {
        const float* ws = (o < 3) ? (w_off + o * (C_ * 3))
                                  : (w_mask + (o - 3) * (C_ * 3));
        const float4* wp = reinterpret_cast<const float4*>(ws + lane * 12);
        float4 q0 = wp[0], q1 = wp[1], q2 = wp[2];
        w_r[o][0]=q0.x; w_r[o][1] =q0.y; w_r[o][2] =q0.z; w_r[o][3] =q0.w;
        w_r[o][4]=q1.x; w_r[o][5] =q1.y; w_r[o][6] =q1.z; w_r[o][7] =q1.w;
        w_r[o][8]=q2.x; w_r[o][9] =q2.y; w_r[o][10]=q2.z; w_r[o][11]=q2.w;
    }

    for (int i = 0; i < TL / 4; ++i) {
        const int ll = g * (TL / 4) + i;
        const int l  = l0 + ll;
        float acc[6] = {0.f, 0.f, 0.f, 0.f, 0.f, 0.f};
        #pragma unroll
        for (int t = 0; t < 3; ++t) {
            const int row = l - 1 + t;
            if (row >= 0 && row < L_) {
                const float4 xv =
                    *reinterpret_cast<const float4*>(xb + (size_t)row * C_ + lane * 4);
                #pragma unroll
                for (int o = 0; o < 6; ++o) {
                    acc[o] += xv.x * w_r[o][0 + t] + xv.y * w_r[o][3 + t]
                            + xv.z * w_r[o][6 + t] + xv.w * w_r[o][9 + t];
                }
            }
        }
        #pragma unroll
        for (int o = 0; o < 6; ++o) {
            #pragma unroll
            for (int s = 32; s > 0; s >>= 1)
                acc[o] += __shfl_xor(acc[o], s, 64);
        }
        if (lane == 0) {
            #pragma unroll
            for (int k = 0; k < 3; ++k) {
                float off = acc[k] + b_off[k];
                float pos = fminf(fmaxf((float)l + off, 0.0f), (float)(L_ - 1));
                float flf = floorf(pos);
                int   fl  = (int)flf;
                int   ce  = min(fl + 1, L_ - 1);
                s_fl[k][ll] = fl;
                s_ce[k][ll] = ce;
                s_al[k][ll] = pos - flf;
                float z = acc[k + 3] + b_mask[k];
                s_mk[k][ll] = 1.0f / (1.0f + __expf(-z));
            }
        }
    }
    __syncthreads();

    {
        const int c = tid;
        #pragma unroll 4
        for (int ll = 0; ll < TL; ++ll) {
            float v = 0.f;
            #pragma unroll
            for (int k = 0; k < 3; ++k) {
                const int   fl = s_fl[k][ll];
                const int   ce = s_ce[k][ll];
                const float a  = s_al[k][ll];
                const float m  = s_mk[k][ll];
                const float xf = xb[fl * C_ + c];
                const float xc = xb[ce * C_ + c];
                v += (xf + a * (xc - xf)) * m;
            }
            s_tile[ll * C_ + (c ^ (ll & 31))] = v;
        }
    }
    __syncthreads();

    {
        const int lw = tid & 31;
        const int cg = tid >> 5;
        #pragma unroll 8
        for (int cc = 0; cc < 32; ++cc) {
            const int c = cg * 32 + cc;
            out[((size_t)b * C_ + c) * L_ + l0 + lw] = s_tile[lw * C_ + (c ^ lw)];
        }
    }
}

extern "C" void kernel_launch(void* const* d_in, const int* in_sizes, int n_in,
                              void* d_out, int out_size, void* d_ws, size_t ws_size,
                              hipStream_t stream) {
    const float* x      = (const float*)d_in[0];
    const float* w_off  = (const float*)d_in[1];
    const float* b_off  = (const float*)d_in[2];
    const float* w_mask = (const float*)d_in[3];
    const float* b_mask = (const float*)d_in[4];
    float* out = (float*)d_out;

    const size_t need = (size_t)B_ * L_ * 3 * sizeof(float4);  // 1.57 MB
    if (ws_size >= need) {
        float4* prm = (float4*)d_ws;
        dim3 gA(L_ / 16, B_);
        params_kernel<<<gA, 256, 0, stream>>>(x, w_off, b_off, w_mask, b_mask, prm);
        dim3 gB((L_ / 32) * (C_ / 64), B_);
        sample_kernel<<<gB, 256, 0, stream>>>(x, prm, out);
    } else {
        dim3 grid(L_ / TL, B_);
        dconv1d_fused<<<grid, 256, 0, stream>>>(x, w_off, b_off, w_mask, b_mask, out);
    }
}

// Round 7
// 34.979 us; speedup vs baseline: 1.5875x; 1.3625x over previous
//
#include <hip/hip_runtime.h>
#include <math.h>

#define B_  8
#define L_  4096
#define C_  256
#define TL  32

// ---- DPP wave-sum on the VALU pipe (no LDS traffic) ----
// Mirror-based sequence (direction-proof). After wave_sum_hi, ALL of
// lanes 48..63 hold the full 64-lane sum.
template<int CTRL, int RM>
__device__ __forceinline__ float dpp_add(float v) {
    int mv = __builtin_amdgcn_update_dpp(0, __float_as_int(v), CTRL, RM, 0xf, true);
    return v + __int_as_float(mv);
}
__device__ __forceinline__ float wave_sum_hi(float v) {
    v = dpp_add<0xB1, 0xf>(v);   // quad_perm [1,0,3,2]  (xor 1)
    v = dpp_add<0x4E, 0xf>(v);   // quad_perm [2,3,0,1]  (xor 2)
    v = dpp_add<0x141, 0xf>(v);  // row_half_mirror      (8-lane allreduce)
    v = dpp_add<0x140, 0xf>(v);  // row_mirror           (16-lane allreduce)
    v = dpp_add<0x142, 0xa>(v);  // row_bcast15 -> rows 1,3
    v = dpp_add<0x143, 0xc>(v);  // row_bcast31 -> rows 2,3 (row 3 = total)
    return v;
}

__global__ __launch_bounds__(256, 4)
void dconv1d_kernel(const float* __restrict__ x,
                    const float* __restrict__ w_off,
                    const float* __restrict__ b_off,
                    const float* __restrict__ w_mask,
                    const float* __restrict__ b_mask,
                    float* __restrict__ out) {
    __shared__ float s_tile[TL * C_];   // 32 KB
    __shared__ int   s_fl[3][TL];
    __shared__ int   s_ce[3][TL];
    __shared__ float s_al[3][TL];
    __shared__ float s_mk[3][TL];

    const int tid  = threadIdx.x;
    const int lane = tid & 63;
    const int g    = tid >> 6;          // wave 0..3
    const int l0   = blockIdx.x * TL;
    const int b    = blockIdx.y;
    const float* __restrict__ xb = x + (size_t)b * L_ * C_;

    // biases (wave-uniform scalars)
    const float bo0 = b_off[0],  bo1 = b_off[1],  bo2 = b_off[2];
    const float bm0 = b_mask[0], bm1 = b_mask[1], bm2 = b_mask[2];

    // weights in registers: lane owns channels lane*4 .. lane*4+3
    float w_r[6][12];
    #pragma unroll
    for (int o = 0; o < 6; ++o) {
        const float* ws = (o < 3) ? (w_off + o * (C_ * 3))
                                  : (w_mask + (o - 3) * (C_ * 3));
        const float4* wp = reinterpret_cast<const float4*>(ws + lane * 12);
        float4 q0 = wp[0], q1 = wp[1], q2 = wp[2];
        w_r[o][0]=q0.x; w_r[o][1] =q0.y; w_r[o][2] =q0.z; w_r[o][3] =q0.w;
        w_r[o][4]=q1.x; w_r[o][5] =q1.y; w_r[o][6] =q1.z; w_r[o][7] =q1.w;
        w_r[o][8]=q2.x; w_r[o][9] =q2.y; w_r[o][10]=q2.z; w_r[o][11]=q2.w;
    }

    // ---- phase 1: conv -> params; wave g owns ll = g*8..g*8+7, 2 batches of 4
    #pragma unroll
    for (int bt = 0; bt < 2; ++bt) {
        const int lb4 = l0 + g * 8 + bt * 4;   // batch's first position
        float acc[4][6];
        #pragma unroll
        for (int i = 0; i < 4; ++i)
            #pragma unroll
            for (int o = 0; o < 6; ++o) acc[i][o] = 0.f;

        // 6 rows cover positions lb4..lb4+3, taps -1..+1 (each row loaded once)
        #pragma unroll
        for (int rr = 0; rr < 6; ++rr) {
            const int row = lb4 - 1 + rr;
            if (row >= 0 && row < L_) {
                const float4 xv = *reinterpret_cast<const float4*>(
                    xb + (size_t)row * C_ + lane * 4);
                #pragma unroll
                for (int t = 0; t < 3; ++t) {
                    const int i = rr - t;          // compile-time per (rr,t)
                    if (i >= 0 && i < 4) {
                        #pragma unroll
                        for (int o = 0; o < 6; ++o)
                            acc[i][o] += xv.x * w_r[o][0 + t] + xv.y * w_r[o][3 + t]
                                       + xv.z * w_r[o][6 + t] + xv.w * w_r[o][9 + t];
                    }
                }
            }
        }

        // VALU-pipe reduction: 24 independent DPP chains, zero DS ops
        #pragma unroll
        for (int i = 0; i < 4; ++i)
            #pragma unroll
            for (int o = 0; o < 6; ++o)
                acc[i][o] = wave_sum_hi(acc[i][o]);

        // writer lanes 48..59: lane 48 + pi*4 + k  (k<3), all sums replicated
        if (lane >= 48) {
            const int idx = lane - 48;     // 0..15
            const int pi  = idx >> 2;      // position in batch
            const int k   = idx & 3;       // tap
            if (k < 3) {
                float so = 0.f, sm = 0.f;
                #pragma unroll
                for (int ii = 0; ii < 4; ++ii)
                    #pragma unroll
                    for (int kk = 0; kk < 3; ++kk)
                        if (((ii << 2) | kk) == idx) {
                            so = acc[ii][kk];
                            sm = acc[ii][kk + 3];
                        }
                const float bo = (k == 0) ? bo0 : ((k == 1) ? bo1 : bo2);
                const float bm = (k == 0) ? bm0 : ((k == 1) ? bm1 : bm2);
                const int ll = g * 8 + bt * 4 + pi;
                const int l  = l0 + ll;
                const float off = so + bo;
                const float pos = fminf(fmaxf((float)l + off, 0.0f), (float)(L_ - 1));
                const float flf = floorf(pos);
                const int   fl  = (int)flf;
                s_fl[k][ll] = fl;
                s_ce[k][ll] = min(fl + 1, L_ - 1);
                s_al[k][ll] = pos - flf;
                s_mk[k][ll] = 1.0f / (1.0f + __expf(-(sm + bm)));
            }
        }
    }
    __syncthreads();

    // ---- phase 2: gather + lerp + mask; thread owns channel c = tid ----
    {
        const int c = tid;
        #pragma unroll 4
        for (int ll = 0; ll < TL; ++ll) {
            float v = 0.f;
            #pragma unroll
            for (int k = 0; k < 3; ++k) {
                const int   fl = s_fl[k][ll];
                const int   ce = s_ce[k][ll];
                const float a  = s_al[k][ll];
                const float m  = s_mk[k][ll];
                const float xf = xb[fl * C_ + c];
                const float xc = xb[ce * C_ + c];
                v += (xf + a * (xc - xf)) * m;
            }
            s_tile[ll * C_ + (c ^ (ll & 31))] = v;
        }
    }
    __syncthreads();

    // ---- phase 3: transpose write-out (full 128B lines along l) ----
    {
        const int lw = tid & 31;
        const int cg = tid >> 5;
        #pragma unroll 8
        for (int cc = 0; cc < 32; ++cc) {
            const int c = cg * 32 + cc;
            out[((size_t)b * C_ + c) * L_ + l0 + lw] = s_tile[lw * C_ + (c ^ lw)];
        }
    }
}

extern "C" void kernel_launch(void* const* d_in, const int* in_sizes, int n_in,
                              void* d_out, int out_size, void* d_ws, size_t ws_size,
                              hipStream_t stream) {
    const float* x      = (const float*)d_in[0];
    const float* w_off  = (const float*)d_in[1];
    const float* b_off  = (const float*)d_in[2];
    const float* w_mask = (const float*)d_in[3];
    const float* b_mask = (const float*)d_in[4];
    float* out = (float*)d_out;

    dim3 grid(L_ / TL, B_);
    dconv1d_kernel<<<grid, 256, 0, stream>>>(x, w_off, b_off, w_mask, b_mask, out);
}